// Round 21
// baseline (482.419 us; speedup 1.0000x reference)
//
#include <hip/hip_runtime.h>
#include <hip/hip_fp16.h>

#define HD 64
#define SEQ 2304

typedef unsigned short u16;
typedef unsigned int u32;
using f32x4 = __attribute__((ext_vector_type(4))) float;
using s16x8 = __attribute__((ext_vector_type(8))) short;

static __device__ __forceinline__ float bf2f(u16 h) {
  union { float f; u32 u; } a; a.u = ((u32)h) << 16; return a.f;
}
// truncation split: x ~= hi + lo, |err| ~ 2^-16 |x|
static __device__ __forceinline__ void split2(float x, u16& h, u16& l) {
  u32 u = __float_as_uint(x);
  h = (u16)(u >> 16);
  float r = x - __uint_as_float(u & 0xffff0000u);
  l = (u16)(__float_as_uint(r) >> 16);
}
// round-to-nearest-even bf16 (unbiased: used for V which is consumed hi-only)
static __device__ __forceinline__ u16 rne_bf16(float x) {
  u32 u = __float_as_uint(x);
  return (u16)((u + 0x7fffu + ((u >> 16) & 1u)) >> 16);
}

// ---------------- convert + transpose BOTH weights: w[768][N] f32 -> wT[N][768]
// bf16 hi/lo. Grid x: [0,36) -> qkv_w (N=2304), [36,48) -> proj_w (N=768).
__global__ __launch_bounds__(256) void conv_wT2_k(
    const float* __restrict__ wq, const float* __restrict__ wp,
    u16* __restrict__ qhiT, u16* __restrict__ qloT,
    u16* __restrict__ phiT, u16* __restrict__ ploT)
{
  __shared__ u32 t[64][65];
  const int tid = threadIdx.x;
  const bool isq = blockIdx.x < 36;
  const int bx = isq ? blockIdx.x : blockIdx.x - 36;
  const float* src = isq ? wq : wp;
  u16* dhi = isq ? qhiT : phiT;
  u16* dlo = isq ? qloT : ploT;
  const int N = isq ? 2304 : 768;
  const int n0 = bx * 64, k0 = blockIdx.y * 64;
  const int r = tid >> 2, c0 = (tid & 3) * 16;
  const float* sp = src + (size_t)(k0 + r) * N + n0 + c0;
#pragma unroll
  for (int j = 0; j < 16; j += 4) {
    f32x4 v = *(const f32x4*)(sp + j);
#pragma unroll
    for (int e = 0; e < 4; e++) {
      u16 h, l;
      split2(v[e], h, l);
      t[r][c0 + j + e] = (u32)h | ((u32)l << 16);
    }
  }
  __syncthreads();
  u16 hb[16], lb[16];
#pragma unroll
  for (int j = 0; j < 16; j++) {
    u32 p = t[c0 + j][r];
    hb[j] = (u16)(p & 0xffffu);
    lb[j] = (u16)(p >> 16);
  }
  size_t off = (size_t)(n0 + r) * 768 + k0 + c0;
  *(uint4*)(dhi + off)     = *(uint4*)&hb[0];
  *(uint4*)(dhi + off + 8) = *(uint4*)&hb[8];
  *(uint4*)(dlo + off)     = *(uint4*)&lb[0];
  *(uint4*)(dlo + off + 8) = *(uint4*)&lb[8];
}

// ---- qkv direct-fragment helpers: A = raw fp32 (split in-register at use)
static __device__ __forceinline__ void loadF(
    const float* pA, const u16* pBh, const u16* pBl, int kk,
    uint4 aw[4][2], s16x8 bh[4], s16x8 bl[4])
{
#pragma unroll
  for (int mt = 0; mt < 4; mt++) {
    size_t o = (size_t)mt * 12288 + (size_t)kk * 32;   // row-stride 768 elems
    aw[mt][0] = *(const uint4*)(pA + o);       // 4 f32 (bits)
    aw[mt][1] = *(const uint4*)(pA + o + 4);
    bh[mt] = *(const s16x8*)(pBh + o);
    bl[mt] = *(const s16x8*)(pBl + o);
  }
}
static __device__ __forceinline__ void mfmaF(
    uint4 aw[4][2], const s16x8 bh[4], const s16x8 bl[4], f32x4 acc[4][4])
{
#pragma unroll
  for (int mt = 0; mt < 4; mt++) {
    u32 w[8];
    *(uint4*)&w[0] = aw[mt][0]; *(uint4*)&w[4] = aw[mt][1];
    u16 hh[8], ll[8];
#pragma unroll
    for (int j = 0; j < 8; j++)
      split2(__uint_as_float(w[j]), hh[j], ll[j]);
    s16x8 ah = *(s16x8*)&hh[0];
    s16x8 al = *(s16x8*)&ll[0];
#pragma unroll
    for (int nt = 0; nt < 4; nt++) {
      acc[mt][nt] = __builtin_amdgcn_mfma_f32_16x16x32_bf16(ah, bh[nt], acc[mt][nt], 0, 0, 0);
      acc[mt][nt] = __builtin_amdgcn_mfma_f32_16x16x32_bf16(ah, bl[nt], acc[mt][nt], 0, 0, 0);
      acc[mt][nt] = __builtin_amdgcn_mfma_f32_16x16x32_bf16(al, bh[nt], acc[mt][nt], 0, 0, 0);
    }
  }
}

// ---------------- QKV GEMM, barrier-free direct-fragment, fp32-A in-register split:
// -> q fp32 + K (hi/lo) + V (single RNE bf16) images.
__global__ __launch_bounds__(256, 2) void qkv_mfma_k(
    const float* __restrict__ x,
    const u16* __restrict__ bthi, const u16* __restrict__ btlo,
    const float* __restrict__ bias,
    float* __restrict__ qbuf, u16* __restrict__ khi, u16* __restrict__ klo,
    u16* __restrict__ vhi)
{
  __shared__ __align__(16) u16 img[4][4096];   // epilogue only (wave-private)
  const int tid = threadIdx.x;
  const int lane = tid & 63, wid = tid >> 6;
  const int g = lane >> 4, ql = lane & 15;
  const int wr = wid >> 1, wc = wid & 1;
  const int c0 = blockIdx.x * 128, r0 = blockIdx.y * 128;

  const float* pA = x    + (size_t)(r0 + wr * 64 + ql) * 768 + g * 8;
  const u16* pBh = bthi + (size_t)(c0 + wc * 64 + ql) * 768 + g * 8;
  const u16* pBl = btlo + (size_t)(c0 + wc * 64 + ql) * 768 + g * 8;

  uint4 Xa[4][2]; s16x8 Xbh[4], Xbl[4];
  uint4 Ya[4][2]; s16x8 Ybh[4], Ybl[4];
  f32x4 acc[4][4] = {};

  loadF(pA, pBh, pBl, 0, Xa, Xbh, Xbl);
  for (int ks = 0; ks < 24; ks += 2) {
    loadF(pA, pBh, pBl, ks + 1, Ya, Ybh, Ybl);
    mfmaF(Xa, Xbh, Xbl, acc);
    if (ks + 2 < 24)
      loadF(pA, pBh, pBl, ks + 2, Xa, Xbh, Xbl);
    mfmaF(Ya, Ybh, Ybl, acc);
  }

  // ---- epilogue: q fp32 scatter / K,V permuted tile-images via LDS (wave-private)
  const int col0 = c0 + wc * 64;
  const int row0 = r0 + wr * 64;
  const int hb36 = col0 >> 6;
  const int which = hb36 / 12, head = hb36 - (hb36 / 12) * 12;
  const int b = row0 / 2304;
  const int sb = row0 - b * 2304;
  const int bh = b * 12 + head;
  float bb[4];
#pragma unroll
  for (int nt = 0; nt < 4; nt++) bb[nt] = bias[col0 + nt * 16 + ql];
#pragma unroll
  for (int mt = 0; mt < 4; mt++)
#pragma unroll
    for (int nt = 0; nt < 4; nt++)
#pragma unroll
      for (int r = 0; r < 4; r++)
        acc[mt][nt][r] += bb[nt];

  if (which == 0) {
#pragma unroll
    for (int mt = 0; mt < 4; mt++)
#pragma unroll
      for (int nt = 0; nt < 4; nt++)
#pragma unroll
        for (int r = 0; r < 4; r++) {
          int s = sb + mt * 16 + g * 4 + r;
          qbuf[((size_t)bh * SEQ + s) * 64 + nt * 16 + ql] = acc[mt][nt][r];
        }
  } else if (which == 1) {
    const int kt = sb >> 6;
    const size_t tile = ((size_t)bh * 36 + kt) * 4096;
    u16* const reg = img[wid];
    // pass 1: HI
#pragma unroll
    for (int mt = 0; mt < 4; mt++)
#pragma unroll
      for (int nt = 0; nt < 4; nt++) {
        int pcK = (nt >> 1) * 32 + (ql >> 2) * 8 + (nt & 1) * 4 + (ql & 3);
#pragma unroll
        for (int r = 0; r < 4; r++) {
          u16 h, l;
          split2(acc[mt][nt][r], h, l);
          reg[(mt * 16 + g * 4 + r) * 64 + pcK] = h;
        }
      }
    {
      const u16* src = reg + lane * 64;
      u16* dst = khi + tile + lane * 64;
#pragma unroll
      for (int j = 0; j < 8; j++)
        *(uint4*)(dst + j * 8) = *(const uint4*)(src + j * 8);
    }
    // pass 2: LO
#pragma unroll
    for (int mt = 0; mt < 4; mt++)
#pragma unroll
      for (int nt = 0; nt < 4; nt++) {
        int pcK = (nt >> 1) * 32 + (ql >> 2) * 8 + (nt & 1) * 4 + (ql & 3);
#pragma unroll
        for (int r = 0; r < 4; r++) {
          u16 h, l;
          split2(acc[mt][nt][r], h, l);
          reg[(mt * 16 + g * 4 + r) * 64 + pcK] = l;
        }
      }
    {
      const u16* src = reg + lane * 64;
      u16* dst = klo + tile + lane * 64;
#pragma unroll
      for (int j = 0; j < 8; j++)
        *(uint4*)(dst + j * 8) = *(const uint4*)(src + j * 8);
    }
  } else {
    // V image: single pass, RNE bf16 (consumed hi-only; RNE kills truncation bias)
    const int kt = sb >> 6;
    const size_t tile = ((size_t)bh * 36 + kt) * 4096;
    u16* const reg = img[wid];
#pragma unroll
    for (int mt = 0; mt < 4; mt++)
#pragma unroll
      for (int nt = 0; nt < 4; nt++)
#pragma unroll
        for (int r = 0; r < 4; r++) {
          int off = (nt * 16 + ql) * 64 + (mt >> 1) * 32 + g * 8 + (mt & 1) * 4 + r;
          reg[off] = rne_bf16(acc[mt][nt][r]);
        }
    {
      const u16* src = reg + lane * 64;
      u16* dst = vhi + tile + lane * 64;
#pragma unroll
      for (int j = 0; j < 8; j++)
        *(uint4*)(dst + j * 8) = *(const uint4*)(src + j * 8);
    }
  }
}

// ---------------- Fused attention: DOUBLE-BUFFERED LDS, ONE barrier per tile.
// Hazards: RAW protected by the barrier (write buf -> barrier -> read buf);
// WAR on buf[(kt+1)&1] protected because its readers (compute kt-1) precede
// barrier(kt) in program order. Halves barrier-convergence events (72 -> 36).
// LDS 62.2KB -> 2 blocks/CU. Bias rotation(3) x parity(2) -> unroll 6.
#define BUFSZ  27648                      // bytes per buffer {Khi,Klo,V} x [64][72]
#define BWS_OFF 27648                     // scratch Bw: aliases buf1 (dead pre-loop)
#define BH_OFF  55296                     // Bh: 49 x 65 u16
#define MS_OFF  (BH_OFF + 6372)           // 61668
#define LS_OFF  (MS_OFF + 256)            // 61924
__global__ __launch_bounds__(512) void attn_k(
    const float* __restrict__ qb,
    const u16* __restrict__ khi, const u16* __restrict__ klo,
    const u16* __restrict__ vhi,
    const float* __restrict__ rph, const float* __restrict__ rpw,
    u32* __restrict__ aop)
{
  __shared__ __align__(16) char pool[LS_OFF + 256];   // 62180 B
  __half* BwS = (__half*)(pool + BWS_OFF); // scratch [48 kw][65 pad]
  __half* Bh  = (__half*)(pool + BH_OFF);  // [49 kh][65 pad]
  float* m_s = (float*)(pool + MS_OFF);    // [64]
  float* l_s = (float*)(pool + LS_OFF);    // [64]
  float* qlds = (float*)pool;              // prologue alias [64][68] f32 (17408B)
  float* o_s  = (float*)pool;              // epilogue alias [64][68] f32

  const int tid  = threadIdx.x;
  const int lane = tid & 63;
  const int wid  = tid >> 6;
  const int g    = lane >> 4;
  const int ql   = lane & 15;
  const int wq   = wid & 3;     // q-group: rows [16*wq, 16*wq+16)
  const int hh   = wid >> 2;    // key-half stream
  const int bh   = blockIdx.x;  // 24
  const int qt   = blockIdx.y;  // 36
  const int s0   = qt * 64;

  // ---- stage Q tile fp32 -> LDS
  {
    int row = tid >> 3, c0 = (tid & 7) * 8;
    const float* src = qb + ((size_t)bh * SEQ + s0 + row) * HD + c0;
    f32x4 v0 = *(const f32x4*)src;
    f32x4 v1 = *(const f32x4*)(src + 4);
    *(f32x4*)&qlds[row * 68 + c0]     = v0;
    *(f32x4*)&qlds[row * 68 + c0 + 4] = v1;
  }
  __syncthreads();

  // ---- Q fragments hi/lo (lane's q = 16*wq + ql)
  s16x8 qfh[2], qfl[2];
  {
    int qrow = wq * 16 + ql;
#pragma unroll
    for (int ds = 0; ds < 2; ds++) {
#pragma unroll
      for (int h2 = 0; h2 < 2; h2++) {
        f32x4 qv = *(const f32x4*)&qlds[qrow * 68 + g * 4 + h2 * 16 + ds * 32];
#pragma unroll
        for (int j = 0; j < 4; j++) {
          u16 hi, lo;
          split2(qv[j], hi, lo);
          qfh[ds][h2 * 4 + j] = (short)hi;
          qfl[ds][h2 * 4 + j] = (short)lo;
        }
      }
    }
  }

  // ---- prefetch tile 0
  const size_t tbK = (size_t)bh * 36 * 4096;
  const int srow = tid >> 3;
  const int sch  = ((tid & 7) - (srow & 7)) & 7;
  const size_t soff = (size_t)srow * 64 + sch * 8;
  uint4 rkh = *(const uint4*)(khi + tbK + soff);
  uint4 rkl = *(const uint4*)(klo + tbK + soff);
  uint4 rvh = *(const uint4*)(vhi + tbK + soff);

  // ---- decomposed rel-pos bias build: Bh persistent, Bw into scratch (buf1 alias)
  for (int i = tid; i < 64 * 96; i += 512) {
    int q = i / 96, j = i - (i / 96) * 96;
    int s = s0 + q;
    int qhg = s / 48, qw = s - qhg * 48;
    const float* tab;
    int ridx, col;
    if (j < 48) { col = j;      ridx = qhg - j + 47;        tab = rph; }
    else        { col = j - 48; ridx = qw - (j - 48) + 47;  tab = rpw; }
    const float* rp = tab + (size_t)ridx * HD;
    const float* qp = &qlds[q * 68];
    float s1 = 0.f;
#pragma unroll 4
    for (int d = 0; d < 64; d += 4) {
      f32x4 a = *(const f32x4*)(qp + d);
      f32x4 bv = *(const f32x4*)(rp + d);
      s1 += a[0]*bv[0] + a[1]*bv[1] + a[2]*bv[2] + a[3]*bv[3];
    }
    if (j < 48) Bh[col * 65 + q] = __float2half_rn(s1);
    else        BwS[col * 65 + q] = __float2half_rn(s1);
  }
  __syncthreads();

  const int q64b = wq * 16 + ql;

  // ---- hoist per-lane Bw values (12), reorder by hh for kt%3 rotation
  float wA[4], wB[4], wC[4];
  {
    float b0[4], b1[4], b2[4];
#pragma unroll
    for (int r = 0; r < 4; r++) {
      b0[r] = __half2float(BwS[(      g * 4 + r) * 65 + q64b]);
      b1[r] = __half2float(BwS[(16 +  g * 4 + r) * 65 + q64b]);
      b2[r] = __half2float(BwS[(32 +  g * 4 + r) * 65 + q64b]);
    }
#pragma unroll
    for (int r = 0; r < 4; r++) {
      wA[r] = hh ? b2[r] : b0[r];   // w[j] = bw[(j + 2*hh) % 3]
      wB[r] = hh ? b0[r] : b1[r];
      wC[r] = hh ? b1[r] : b2[r];
    }
  }

  float m_r = -3.0e38f, l_r = 0.f;   // l_r = per-lane partial (reduced in epilogue)
  f32x4 oacc[4] = {};   // O[q = 4g+r][d = ql + 16*dt]

  // tile body: CUR = kt&1 buffer; ONE barrier per tile (write -> barrier -> compute)
#define ATTN_TILE(KT, WA_, WB_, WRAP1, CUR) {                                   \
    const int kt = (KT);                                                        \
    u16* const Kb = (u16*)(pool + (CUR) * BUFSZ);                               \
    *(uint4*)(Kb + srow * 72 + sch * 8) = rkh;                                  \
    *(uint4*)(Kb + 4608 + srow * 72 + sch * 8) = rkl;                           \
    *(uint4*)(Kb + 9216 + srow * 72 + sch * 8) = rvh;                           \
    __syncthreads();                                                            \
    if (kt < 35) {                                                              \
      size_t tb = tbK + (size_t)(kt + 1) * 4096;                                \
      rkh = *(const uint4*)(khi + tb + soff);                                   \
      rkl = *(const uint4*)(klo + tb + soff);                                   \
      rvh = *(const uint4*)(vhi + tb + soff);                                   \
    }                                                                           \
    f32x4 sacc[2] = {};                                                         \
    _Pragma("unroll")                                                           \
    for (int ds = 0; ds < 2; ds++) {                                            \
      _Pragma("unroll")                                                         \
      for (int t2 = 0; t2 < 2; t2++) {                                          \
        int row = (hh * 2 + t2) * 16 + ql;                                      \
        s16x8 af = *(const s16x8*)(Kb + row * 72 + ds * 32 + g * 8);            \
        s16x8 al = *(const s16x8*)(Kb + 4608 + row * 72 + ds * 32 + g * 8);     \
        sacc[t2] = __builtin_amdgcn_mfma_f32_16x16x32_bf16(af, qfh[ds], sacc[t2], 0, 0, 0); \
        sacc[t2] = __builtin_amdgcn_mfma_f32_16x16x32_bf16(af, qfl[ds], sacc[t2], 0, 0, 0); \
        sacc[t2] = __builtin_amdgcn_mfma_f32_16x16x32_bf16(al, qfh[ds], sacc[t2], 0, 0, 0); \
      }                                                                         \
    }                                                                           \
    u32 kg0 = (u32)(kt * 64 + hh * 32);                                         \
    u32 kh0 = kg0 / 48u;                                                        \
    float bh0v = __half2float(Bh[kh0 * 65 + q64b]);                             \
    float bh1v = __half2float(Bh[(kh0 + 1) * 65 + q64b]);                       \
    float bhB = (WRAP1) ? bh1v : bh0v;                                          \
    float lg[8];                                                                \
    float tmax = -3.0e38f;                                                      \
    _Pragma("unroll")                                                           \
    for (int r = 0; r < 4; r++) {                                               \
      float x0 = sacc[0][r] * 0.125f + (bh0v + WA_[r]);                         \
      float x1 = sacc[1][r] * 0.125f + (bhB  + WB_[r]);                         \
      lg[r]     = x0;                                                           \
      lg[4 + r] = x1;                                                           \
      tmax = fmaxf(tmax, fmaxf(x0, x1));                                       \
    }                                                                           \
    tmax = fmaxf(tmax, __shfl_xor(tmax, 16));                                   \
    tmax = fmaxf(tmax, __shfl_xor(tmax, 32));                                   \
    if (__any(tmax > m_r + 6.0f)) {                                             \
      float mnew = fmaxf(m_r, tmax);                                            \
      float corr = __expf(m_r - mnew);                                          \
      l_r *= corr;                                                              \
      m_r = mnew;                                                               \
      float cq[4];                                                              \
      _Pragma("unroll")                                                         \
      for (int r = 0; r < 4; r++) cq[r] = __shfl(corr, g * 4 + r);              \
      _Pragma("unroll")                                                         \
      for (int dt = 0; dt < 4; dt++)                                            \
        _Pragma("unroll")                                                       \
        for (int r = 0; r < 4; r++) oacc[dt][r] *= cq[r];                       \
    }                                                                           \
    float psum = 0.f;                                                           \
    s16x8 pfh;                                                                  \
    _Pragma("unroll")                                                           \
    for (int j = 0; j < 8; j++) {                                               \
      float p = __expf(lg[j] - m_r);                                            \
      psum += p;                                                                \
      pfh[j] = (short)(u16)(__float_as_uint(p) >> 16);                          \
    }                                                                           \
    l_r += psum;                                                                \
    _Pragma("unroll")                                                           \
    for (int dt = 0; dt < 4; dt++) {                                            \
      int row = ql + 16 * dt;                                                   \
      s16x8 bhf = *(const s16x8*)(Kb + 9216 + row * 72 + hh * 32 + g * 8);      \
      oacc[dt] = __builtin_amdgcn_mfma_f32_16x16x32_bf16(pfh, bhf, oacc[dt], 0, 0, 0); \
    }                                                                           \
  }

  for (int kt0 = 0; kt0 < 36; kt0 += 6) {
    ATTN_TILE(kt0 + 0, wA, wB, hh != 0, 0);
    ATTN_TILE(kt0 + 1, wB, wC, false,   1);
    ATTN_TILE(kt0 + 2, wC, wA, hh == 0, 0);
    ATTN_TILE(kt0 + 3, wA, wB, hh != 0, 1);
    ATTN_TILE(kt0 + 4, wB, wC, false,   0);
    ATTN_TILE(kt0 + 5, wC, wA, hh == 0, 1);
  }
#undef ATTN_TILE

  // ---- deferred cross-g reduction of per-lane partial l
  l_r += __shfl_xor(l_r, 16);
  l_r += __shfl_xor(l_r, 32);

  // ---- merge the two key-streams per q-group, write out (packed u32 hi|lo)
  __syncthreads();
  if (hh == 1) {
    if (g == 0) { m_s[q64b] = m_r; l_s[q64b] = l_r; }
#pragma unroll
    for (int dt = 0; dt < 4; dt++)
#pragma unroll
      for (int r = 0; r < 4; r++)
        o_s[(wq * 16 + g * 4 + r) * 68 + ql + 16 * dt] = oacc[dt][r];
  }
  __syncthreads();
  if (hh == 0) {
    float m2 = m_s[q64b];
    float l2 = l_s[q64b];
    float mf = fmaxf(m_r, m2);
    float c1 = __expf(m_r - mf);
    float c2 = __expf(m2 - mf);
    float lf = l_r * c1 + l2 * c2;
    float c1q[4], c2q[4], lfq[4];
#pragma unroll
    for (int r = 0; r < 4; r++) {
      c1q[r] = __shfl(c1, g * 4 + r);
      c2q[r] = __shfl(c2, g * 4 + r);
      lfq[r] = __shfl(lf, g * 4 + r);
    }
    const int b = bh / 12, head = bh - (bh / 12) * 12;
#pragma unroll
    for (int dt = 0; dt < 4; dt++)
#pragma unroll
      for (int r = 0; r < 4; r++) {
        float oo = oacc[dt][r] * c1q[r]
                 + o_s[(wq * 16 + g * 4 + r) * 68 + ql + 16 * dt] * c2q[r];
        float on = oo / lfq[r];
        int s = s0 + wq * 16 + g * 4 + r;
        size_t idx = ((size_t)b * SEQ + s) * 768 + head * 64 + ql + 16 * dt;
        u16 h, l;
        split2(on, h, l);
        aop[idx] = (u32)h | ((u32)l << 16);
      }
  }
}

// ---- proj direct-fragment helpers: A = packed u32 (unpack in-register)
static __device__ __forceinline__ void unpack8(
    const uint4 w0, const uint4 w1, s16x8& h, s16x8& l)
{
  u32 w[8];
  *(uint4*)&w[0] = w0; *(uint4*)&w[4] = w1;
  u32 hw[4], lw[4];
#pragma unroll
  for (int i = 0; i < 4; i++) {
    hw[i] = (w[2*i] & 0xffffu) | (w[2*i+1] << 16);
    lw[i] = (w[2*i] >> 16) | (w[2*i+1] & 0xffff0000u);
  }
  h = *(s16x8*)&hw[0];
  l = *(s16x8*)&lw[0];
}
static __device__ __forceinline__ void loadP(
    const u32* pA, const u16* pBh, const u16* pBl, int kk,
    uint4 aw[4][2], s16x8 bh[4], s16x8 bl[4])
{
#pragma unroll
  for (int mt = 0; mt < 4; mt++) {
    size_t oa = (size_t)mt * 12288 + (size_t)kk * 32;
    aw[mt][0] = *(const uint4*)(pA + oa);
    aw[mt][1] = *(const uint4*)(pA + oa + 4);
    size_t ob = (size_t)mt * 12288 + (size_t)kk * 32;
    bh[mt] = *(const s16x8*)(pBh + ob);
    bl[mt] = *(const s16x8*)(pBl + ob);
  }
}
static __device__ __forceinline__ void mfmaP(
    uint4 aw[4][2], const s16x8 bh[4], const s16x8 bl[4], f32x4 acc[4][4])
{
#pragma unroll
  for (int mt = 0; mt < 4; mt++) {
    s16x8 ah, al;
    unpack8(aw[mt][0], aw[mt][1], ah, al);
#pragma unroll
    for (int nt = 0; nt < 4; nt++) {
      acc[mt][nt] = __builtin_amdgcn_mfma_f32_16x16x32_bf16(ah, bh[nt], acc[mt][nt], 0, 0, 0);
      acc[mt][nt] = __builtin_amdgcn_mfma_f32_16x16x32_bf16(ah, bl[nt], acc[mt][nt], 0, 0, 0);
      acc[mt][nt] = __builtin_amdgcn_mfma_f32_16x16x32_bf16(al, bh[nt], acc[mt][nt], 0, 0, 0);
    }
  }
}

// ---------------- proj GEMM, barrier-free direct-fragment (qkv-style): -> out
__global__ __launch_bounds__(256, 2) void proj_mfma_k(
    const u32* __restrict__ aop,
    const u16* __restrict__ bthi, const u16* __restrict__ btlo,
    const float* __restrict__ bias, float* __restrict__ out)
{
  const int tid = threadIdx.x;
  const int lane = tid & 63, wid = tid >> 6;
  const int g = lane >> 4, ql = lane & 15;
  const int wr = wid >> 1, wc = wid & 1;
  const int c0 = blockIdx.x * 128, r0 = blockIdx.y * 128;

  const u32* pA  = aop  + (size_t)(r0 + wr * 64 + ql) * 768 + g * 8;
  const u16* pBh = bthi + (size_t)(c0 + wc * 64 + ql) * 768 + g * 8;
  const u16* pBl = btlo + (size_t)(c0 + wc * 64 + ql) * 768 + g * 8;

  uint4 Xa[4][2]; s16x8 Xbh[4], Xbl[4];
  uint4 Ya[4][2]; s16x8 Ybh[4], Ybl[4];
  f32x4 acc[4][4] = {};

  loadP(pA, pBh, pBl, 0, Xa, Xbh, Xbl);
  for (int ks = 0; ks < 24; ks += 2) {
    loadP(pA, pBh, pBl, ks + 1, Ya, Ybh, Ybl);
    mfmaP(Xa, Xbh, Xbl, acc);
    if (ks + 2 < 24)
      loadP(pA, pBh, pBl, ks + 2, Xa, Xbh, Xbl);
    mfmaP(Ya, Ybh, Ybl, acc);
  }

  const int col0 = c0 + wc * 64;
  const int row0 = r0 + wr * 64;
  float bb[4];
#pragma unroll
  for (int nt = 0; nt < 4; nt++) bb[nt] = bias[col0 + nt * 16 + ql];
#pragma unroll
  for (int mt = 0; mt < 4; mt++)
#pragma unroll
    for (int nt = 0; nt < 4; nt++)
#pragma unroll
      for (int r = 0; r < 4; r++)
        out[(size_t)(row0 + mt * 16 + g * 4 + r) * 768 + col0 + nt * 16 + ql] =
            acc[mt][nt][r] + bb[nt];
}

extern "C" void kernel_launch(void* const* d_in, const int* in_sizes, int n_in,
                              void* d_out, int out_size, void* d_ws, size_t ws_size,
                              hipStream_t stream) {
  const float* x      = (const float*)d_in[0];
  const float* qkv_w  = (const float*)d_in[1];
  const float* qkv_b  = (const float*)d_in[2];
  const float* proj_w = (const float*)d_in[3];
  const float* proj_b = (const float*)d_in[4];
  const float* rph    = (const float*)d_in[5];
  const float* rpw    = (const float*)d_in[6];
  float* out = (float*)d_out;
  float* ws  = (float*)d_ws;

  const size_t SZ = (size_t)24 * SEQ * HD;   // 3,538,944 elems (== 4608*768)
  float* qbuf = ws;                          // SZ f32
  u16* khi = (u16*)(ws + SZ);                // khi, klo, vhi (+dead slot)
  u16* klo = khi + SZ;
  u16* vhi = klo + SZ;
  u32* aop = (u32*)(ws + 4 * SZ);            // SZ u32 (packed hi|lo)
  u16* wqThi = (u16*)(ws + 5 * SZ);          // 768*2304 x2
  u16* wqTlo = wqThi + 768 * 2304;
  u16* wpThi = wqTlo + 768 * 2304;           // 768*768 x2
  u16* wpTlo = wpThi + 768 * 768;

  conv_wT2_k <<<dim3(48, 12), 256, 0, stream>>>(qkv_w, proj_w,
                                                wqThi, wqTlo, wpThi, wpTlo);
  qkv_mfma_k <<<dim3(18, 36), 256, 0, stream>>>(x, wqThi, wqTlo, qkv_b,
                                                qbuf, khi, klo, vhi);
  attn_k     <<<dim3(24, 36), 512, 0, stream>>>(qbuf, khi, klo, vhi, rph, rpw, aop);
  proj_mfma_k<<<dim3(6, 36), 256, 0, stream>>>(aop, wpThi, wpTlo, proj_b, out);
}

// Round 22
// 446.874 us; speedup vs baseline: 1.0795x; 1.0795x over previous
//
#include <hip/hip_runtime.h>
#include <hip/hip_fp16.h>

#define HD 64
#define SEQ 2304

typedef unsigned short u16;
typedef unsigned int u32;
using f32x4 = __attribute__((ext_vector_type(4))) float;
using s16x8 = __attribute__((ext_vector_type(8))) short;

static __device__ __forceinline__ float bf2f(u16 h) {
  union { float f; u32 u; } a; a.u = ((u32)h) << 16; return a.f;
}
// truncation split: x ~= hi + lo, |err| ~ 2^-16 |x|
static __device__ __forceinline__ void split2(float x, u16& h, u16& l) {
  u32 u = __float_as_uint(x);
  h = (u16)(u >> 16);
  float r = x - __uint_as_float(u & 0xffff0000u);
  l = (u16)(__float_as_uint(r) >> 16);
}
// round-to-nearest-even bf16 (unbiased: used for V which is consumed hi-only)
static __device__ __forceinline__ u16 rne_bf16(float x) {
  u32 u = __float_as_uint(x);
  return (u16)((u + 0x7fffu + ((u >> 16) & 1u)) >> 16);
}

// ---------------- convert + transpose BOTH weights: w[768][N] f32 -> wT[N][768]
// bf16 hi/lo. Grid x: [0,36) -> qkv_w (N=2304), [36,48) -> proj_w (N=768).
__global__ __launch_bounds__(256) void conv_wT2_k(
    const float* __restrict__ wq, const float* __restrict__ wp,
    u16* __restrict__ qhiT, u16* __restrict__ qloT,
    u16* __restrict__ phiT, u16* __restrict__ ploT)
{
  __shared__ u32 t[64][65];
  const int tid = threadIdx.x;
  const bool isq = blockIdx.x < 36;
  const int bx = isq ? blockIdx.x : blockIdx.x - 36;
  const float* src = isq ? wq : wp;
  u16* dhi = isq ? qhiT : phiT;
  u16* dlo = isq ? qloT : ploT;
  const int N = isq ? 2304 : 768;
  const int n0 = bx * 64, k0 = blockIdx.y * 64;
  const int r = tid >> 2, c0 = (tid & 3) * 16;
  const float* sp = src + (size_t)(k0 + r) * N + n0 + c0;
#pragma unroll
  for (int j = 0; j < 16; j += 4) {
    f32x4 v = *(const f32x4*)(sp + j);
#pragma unroll
    for (int e = 0; e < 4; e++) {
      u16 h, l;
      split2(v[e], h, l);
      t[r][c0 + j + e] = (u32)h | ((u32)l << 16);
    }
  }
  __syncthreads();
  u16 hb[16], lb[16];
#pragma unroll
  for (int j = 0; j < 16; j++) {
    u32 p = t[c0 + j][r];
    hb[j] = (u16)(p & 0xffffu);
    lb[j] = (u16)(p >> 16);
  }
  size_t off = (size_t)(n0 + r) * 768 + k0 + c0;
  *(uint4*)(dhi + off)     = *(uint4*)&hb[0];
  *(uint4*)(dhi + off + 8) = *(uint4*)&hb[8];
  *(uint4*)(dlo + off)     = *(uint4*)&lb[0];
  *(uint4*)(dlo + off + 8) = *(uint4*)&lb[8];
}

// ---- qkv direct-fragment helpers: A = raw fp32 (split in-register at use)
static __device__ __forceinline__ void loadF(
    const float* pA, const u16* pBh, const u16* pBl, int kk,
    uint4 aw[4][2], s16x8 bh[4], s16x8 bl[4])
{
#pragma unroll
  for (int mt = 0; mt < 4; mt++) {
    size_t o = (size_t)mt * 12288 + (size_t)kk * 32;   // row-stride 768 elems
    aw[mt][0] = *(const uint4*)(pA + o);       // 4 f32 (bits)
    aw[mt][1] = *(const uint4*)(pA + o + 4);
    bh[mt] = *(const s16x8*)(pBh + o);
    bl[mt] = *(const s16x8*)(pBl + o);
  }
}
static __device__ __forceinline__ void mfmaF(
    uint4 aw[4][2], const s16x8 bh[4], const s16x8 bl[4], f32x4 acc[4][4])
{
#pragma unroll
  for (int mt = 0; mt < 4; mt++) {
    u32 w[8];
    *(uint4*)&w[0] = aw[mt][0]; *(uint4*)&w[4] = aw[mt][1];
    u16 hh[8], ll[8];
#pragma unroll
    for (int j = 0; j < 8; j++)
      split2(__uint_as_float(w[j]), hh[j], ll[j]);
    s16x8 ah = *(s16x8*)&hh[0];
    s16x8 al = *(s16x8*)&ll[0];
#pragma unroll
    for (int nt = 0; nt < 4; nt++) {
      acc[mt][nt] = __builtin_amdgcn_mfma_f32_16x16x32_bf16(ah, bh[nt], acc[mt][nt], 0, 0, 0);
      acc[mt][nt] = __builtin_amdgcn_mfma_f32_16x16x32_bf16(ah, bl[nt], acc[mt][nt], 0, 0, 0);
      acc[mt][nt] = __builtin_amdgcn_mfma_f32_16x16x32_bf16(al, bh[nt], acc[mt][nt], 0, 0, 0);
    }
  }
}

// ---------------- QKV GEMM, barrier-free direct-fragment, fp32-A in-register split:
// -> q fp32 + K (hi/lo) + V (single RNE bf16) images.
__global__ __launch_bounds__(256, 2) void qkv_mfma_k(
    const float* __restrict__ x,
    const u16* __restrict__ bthi, const u16* __restrict__ btlo,
    const float* __restrict__ bias,
    float* __restrict__ qbuf, u16* __restrict__ khi, u16* __restrict__ klo,
    u16* __restrict__ vhi)
{
  __shared__ __align__(16) u16 img[4][4096];   // epilogue only (wave-private)
  const int tid = threadIdx.x;
  const int lane = tid & 63, wid = tid >> 6;
  const int g = lane >> 4, ql = lane & 15;
  const int wr = wid >> 1, wc = wid & 1;
  const int c0 = blockIdx.x * 128, r0 = blockIdx.y * 128;

  const float* pA = x    + (size_t)(r0 + wr * 64 + ql) * 768 + g * 8;
  const u16* pBh = bthi + (size_t)(c0 + wc * 64 + ql) * 768 + g * 8;
  const u16* pBl = btlo + (size_t)(c0 + wc * 64 + ql) * 768 + g * 8;

  uint4 Xa[4][2]; s16x8 Xbh[4], Xbl[4];
  uint4 Ya[4][2]; s16x8 Ybh[4], Ybl[4];
  f32x4 acc[4][4] = {};

  loadF(pA, pBh, pBl, 0, Xa, Xbh, Xbl);
  for (int ks = 0; ks < 24; ks += 2) {
    loadF(pA, pBh, pBl, ks + 1, Ya, Ybh, Ybl);
    mfmaF(Xa, Xbh, Xbl, acc);
    if (ks + 2 < 24)
      loadF(pA, pBh, pBl, ks + 2, Xa, Xbh, Xbl);
    mfmaF(Ya, Ybh, Ybl, acc);
  }

  // ---- epilogue: q fp32 scatter / K,V permuted tile-images via LDS (wave-private)
  const int col0 = c0 + wc * 64;
  const int row0 = r0 + wr * 64;
  const int hb36 = col0 >> 6;
  const int which = hb36 / 12, head = hb36 - (hb36 / 12) * 12;
  const int b = row0 / 2304;
  const int sb = row0 - b * 2304;
  const int bh = b * 12 + head;
  float bb[4];
#pragma unroll
  for (int nt = 0; nt < 4; nt++) bb[nt] = bias[col0 + nt * 16 + ql];
#pragma unroll
  for (int mt = 0; mt < 4; mt++)
#pragma unroll
    for (int nt = 0; nt < 4; nt++)
#pragma unroll
      for (int r = 0; r < 4; r++)
        acc[mt][nt][r] += bb[nt];

  if (which == 0) {
#pragma unroll
    for (int mt = 0; mt < 4; mt++)
#pragma unroll
      for (int nt = 0; nt < 4; nt++)
#pragma unroll
        for (int r = 0; r < 4; r++) {
          int s = sb + mt * 16 + g * 4 + r;
          qbuf[((size_t)bh * SEQ + s) * 64 + nt * 16 + ql] = acc[mt][nt][r];
        }
  } else if (which == 1) {
    const int kt = sb >> 6;
    const size_t tile = ((size_t)bh * 36 + kt) * 4096;
    u16* const reg = img[wid];
    // pass 1: HI
#pragma unroll
    for (int mt = 0; mt < 4; mt++)
#pragma unroll
      for (int nt = 0; nt < 4; nt++) {
        int pcK = (nt >> 1) * 32 + (ql >> 2) * 8 + (nt & 1) * 4 + (ql & 3);
#pragma unroll
        for (int r = 0; r < 4; r++) {
          u16 h, l;
          split2(acc[mt][nt][r], h, l);
          reg[(mt * 16 + g * 4 + r) * 64 + pcK] = h;
        }
      }
    {
      const u16* src = reg + lane * 64;
      u16* dst = khi + tile + lane * 64;
#pragma unroll
      for (int j = 0; j < 8; j++)
        *(uint4*)(dst + j * 8) = *(const uint4*)(src + j * 8);
    }
    // pass 2: LO
#pragma unroll
    for (int mt = 0; mt < 4; mt++)
#pragma unroll
      for (int nt = 0; nt < 4; nt++) {
        int pcK = (nt >> 1) * 32 + (ql >> 2) * 8 + (nt & 1) * 4 + (ql & 3);
#pragma unroll
        for (int r = 0; r < 4; r++) {
          u16 h, l;
          split2(acc[mt][nt][r], h, l);
          reg[(mt * 16 + g * 4 + r) * 64 + pcK] = l;
        }
      }
    {
      const u16* src = reg + lane * 64;
      u16* dst = klo + tile + lane * 64;
#pragma unroll
      for (int j = 0; j < 8; j++)
        *(uint4*)(dst + j * 8) = *(const uint4*)(src + j * 8);
    }
  } else {
    // V image: single pass, RNE bf16 (consumed hi-only; RNE kills truncation bias)
    const int kt = sb >> 6;
    const size_t tile = ((size_t)bh * 36 + kt) * 4096;
    u16* const reg = img[wid];
#pragma unroll
    for (int mt = 0; mt < 4; mt++)
#pragma unroll
      for (int nt = 0; nt < 4; nt++)
#pragma unroll
        for (int r = 0; r < 4; r++) {
          int off = (nt * 16 + ql) * 64 + (mt >> 1) * 32 + g * 8 + (mt & 1) * 4 + r;
          reg[off] = rne_bf16(acc[mt][nt][r]);
        }
    {
      const u16* src = reg + lane * 64;
      u16* dst = vhi + tile + lane * 64;
#pragma unroll
      for (int j = 0; j < 8; j++)
        *(uint4*)(dst + j * 8) = *(const uint4*)(src + j * 8);
    }
  }
}

// ---------------- Fused attention (r19/r20 best-known: 275us): 2-barrier staged,
// deferred psum, hoisted Bw, no setprio, single-MFMA PV, LDS 34.8KB.
#define BWS_OFF 18432                     // scratch: aliases VhL (dead pre-loop)
#define BH_OFF  27648                     // Bh: 49 x 65 u16 (row 48 = wrap slack)
#define MS_OFF  (BH_OFF + 6372)           // 34020
#define LS_OFF  (MS_OFF + 256)            // 34276
__global__ __launch_bounds__(512) void attn_k(
    const float* __restrict__ qb,
    const u16* __restrict__ khi, const u16* __restrict__ klo,
    const u16* __restrict__ vhi,
    const float* __restrict__ rph, const float* __restrict__ rpw,
    u32* __restrict__ aop)
{
  __shared__ __align__(16) char pool[LS_OFF + 256];   // 34532 B
  u16* KhiL = (u16*)pool;              // [64 key][72]
  u16* KloL = (u16*)(pool + 9216);
  u16* VhL  = (u16*)(pool + 18432);    // [64 d][72]
  __half* BwS = (__half*)(pool + BWS_OFF); // scratch [48 kw][65 pad]
  __half* Bh  = (__half*)(pool + BH_OFF);  // [49 kh][65 pad]
  float* m_s = (float*)(pool + MS_OFF);    // [64]
  float* l_s = (float*)(pool + LS_OFF);    // [64]
  float* qlds = (float*)pool;              // prologue alias [64][68] f32 (17408B)
  float* o_s  = (float*)pool;              // epilogue alias [64][68] f32

  const int tid  = threadIdx.x;
  const int lane = tid & 63;
  const int wid  = tid >> 6;
  const int g    = lane >> 4;
  const int ql   = lane & 15;
  const int wq   = wid & 3;     // q-group: rows [16*wq, 16*wq+16)
  const int hh   = wid >> 2;    // key-half stream
  const int bh   = blockIdx.x;  // 24
  const int qt   = blockIdx.y;  // 36
  const int s0   = qt * 64;

  // ---- stage Q tile fp32 -> LDS
  {
    int row = tid >> 3, c0 = (tid & 7) * 8;
    const float* src = qb + ((size_t)bh * SEQ + s0 + row) * HD + c0;
    f32x4 v0 = *(const f32x4*)src;
    f32x4 v1 = *(const f32x4*)(src + 4);
    *(f32x4*)&qlds[row * 68 + c0]     = v0;
    *(f32x4*)&qlds[row * 68 + c0 + 4] = v1;
  }
  __syncthreads();

  // ---- Q fragments hi/lo (lane's q = 16*wq + ql)
  s16x8 qfh[2], qfl[2];
  {
    int qrow = wq * 16 + ql;
#pragma unroll
    for (int ds = 0; ds < 2; ds++) {
#pragma unroll
      for (int h2 = 0; h2 < 2; h2++) {
        f32x4 qv = *(const f32x4*)&qlds[qrow * 68 + g * 4 + h2 * 16 + ds * 32];
#pragma unroll
        for (int j = 0; j < 4; j++) {
          u16 hi, lo;
          split2(qv[j], hi, lo);
          qfh[ds][h2 * 4 + j] = (short)hi;
          qfl[ds][h2 * 4 + j] = (short)lo;
        }
      }
    }
  }

  // ---- prefetch tile 0
  const size_t tbK = (size_t)bh * 36 * 4096;
  const int srow = tid >> 3;
  const int sch  = ((tid & 7) - (srow & 7)) & 7;
  const size_t soff = (size_t)srow * 64 + sch * 8;
  uint4 rkh = *(const uint4*)(khi + tbK + soff);
  uint4 rkl = *(const uint4*)(klo + tbK + soff);
  uint4 rvh = *(const uint4*)(vhi + tbK + soff);

  // ---- decomposed rel-pos bias build: Bh persistent, Bw into scratch
  for (int i = tid; i < 64 * 96; i += 512) {
    int q = i / 96, j = i - (i / 96) * 96;
    int s = s0 + q;
    int qhg = s / 48, qw = s - qhg * 48;
    const float* tab;
    int ridx, col;
    if (j < 48) { col = j;      ridx = qhg - j + 47;        tab = rph; }
    else        { col = j - 48; ridx = qw - (j - 48) + 47;  tab = rpw; }
    const float* rp = tab + (size_t)ridx * HD;
    const float* qp = &qlds[q * 68];
    float s1 = 0.f;
#pragma unroll 4
    for (int d = 0; d < 64; d += 4) {
      f32x4 a = *(const f32x4*)(qp + d);
      f32x4 bv = *(const f32x4*)(rp + d);
      s1 += a[0]*bv[0] + a[1]*bv[1] + a[2]*bv[2] + a[3]*bv[3];
    }
    if (j < 48) Bh[col * 65 + q] = __float2half_rn(s1);
    else        BwS[col * 65 + q] = __float2half_rn(s1);
  }
  __syncthreads();

  const int q64b = wq * 16 + ql;

  // ---- hoist per-lane Bw values (12 of them), reorder by hh for kt%3 rotation
  float wA[4], wB[4], wC[4];
  {
    float b0[4], b1[4], b2[4];
#pragma unroll
    for (int r = 0; r < 4; r++) {
      b0[r] = __half2float(BwS[(      g * 4 + r) * 65 + q64b]);
      b1[r] = __half2float(BwS[(16 +  g * 4 + r) * 65 + q64b]);
      b2[r] = __half2float(BwS[(32 +  g * 4 + r) * 65 + q64b]);
    }
#pragma unroll
    for (int r = 0; r < 4; r++) {
      wA[r] = hh ? b2[r] : b0[r];   // w[j] = bw[(j + 2*hh) % 3]
      wB[r] = hh ? b0[r] : b1[r];
      wC[r] = hh ? b1[r] : b2[r];
    }
  }

  float m_r = -3.0e38f, l_r = 0.f;   // l_r = per-lane partial (reduced in epilogue)
  f32x4 oacc[4] = {};   // O[q = 4g+r][d = ql + 16*dt]

  // tile body: WA_ = bw for t2=0, WB_ = bw for t2=1; WRAP1 = (u==2), u=(kt+2hh)%3
#define ATTN_TILE(KT, WA_, WB_, WRAP1) {                                        \
    const int kt = (KT);                                                        \
    __syncthreads();                                                            \
    *(uint4*)(KhiL + srow * 72 + sch * 8) = rkh;                                \
    *(uint4*)(KloL + srow * 72 + sch * 8) = rkl;                                \
    *(uint4*)(VhL  + srow * 72 + sch * 8) = rvh;                                \
    __syncthreads();                                                            \
    if (kt < 35) {                                                              \
      size_t tb = tbK + (size_t)(kt + 1) * 4096;                                \
      rkh = *(const uint4*)(khi + tb + soff);                                   \
      rkl = *(const uint4*)(klo + tb + soff);                                   \
      rvh = *(const uint4*)(vhi + tb + soff);                                   \
    }                                                                           \
    f32x4 sacc[2] = {};                                                         \
    _Pragma("unroll")                                                           \
    for (int ds = 0; ds < 2; ds++) {                                            \
      _Pragma("unroll")                                                         \
      for (int t2 = 0; t2 < 2; t2++) {                                          \
        int row = (hh * 2 + t2) * 16 + ql;                                      \
        s16x8 af = *(const s16x8*)(KhiL + row * 72 + ds * 32 + g * 8);          \
        s16x8 al = *(const s16x8*)(KloL + row * 72 + ds * 32 + g * 8);          \
        sacc[t2] = __builtin_amdgcn_mfma_f32_16x16x32_bf16(af, qfh[ds], sacc[t2], 0, 0, 0); \
        sacc[t2] = __builtin_amdgcn_mfma_f32_16x16x32_bf16(af, qfl[ds], sacc[t2], 0, 0, 0); \
        sacc[t2] = __builtin_amdgcn_mfma_f32_16x16x32_bf16(al, qfh[ds], sacc[t2], 0, 0, 0); \
      }                                                                         \
    }                                                                           \
    u32 kg0 = (u32)(kt * 64 + hh * 32);                                         \
    u32 kh0 = kg0 / 48u;                                                        \
    float bh0v = __half2float(Bh[kh0 * 65 + q64b]);                             \
    float bh1v = __half2float(Bh[(kh0 + 1) * 65 + q64b]);                       \
    float bhB = (WRAP1) ? bh1v : bh0v;                                          \
    float lg[8];                                                                \
    float tmax = -3.0e38f;                                                      \
    _Pragma("unroll")                                                           \
    for (int r = 0; r < 4; r++) {                                               \
      float x0 = sacc[0][r] * 0.125f + (bh0v + WA_[r]);                         \
      float x1 = sacc[1][r] * 0.125f + (bhB  + WB_[r]);                         \
      lg[r]     = x0;                                                           \
      lg[4 + r] = x1;                                                           \
      tmax = fmaxf(tmax, fmaxf(x0, x1));                                        \
    }                                                                           \
    tmax = fmaxf(tmax, __shfl_xor(tmax, 16));                                   \
    tmax = fmaxf(tmax, __shfl_xor(tmax, 32));                                   \
    if (__any(tmax > m_r + 6.0f)) {                                             \
      float mnew = fmaxf(m_r, tmax);                                            \
      float corr = __expf(m_r - mnew);                                          \
      l_r *= corr;                                                              \
      m_r = mnew;                                                               \
      float cq[4];                                                              \
      _Pragma("unroll")                                                         \
      for (int r = 0; r < 4; r++) cq[r] = __shfl(corr, g * 4 + r);              \
      _Pragma("unroll")                                                         \
      for (int dt = 0; dt < 4; dt++)                                            \
        _Pragma("unroll")                                                       \
        for (int r = 0; r < 4; r++) oacc[dt][r] *= cq[r];                       \
    }                                                                           \
    float psum = 0.f;                                                           \
    s16x8 pfh;                                                                  \
    _Pragma("unroll")                                                           \
    for (int j = 0; j < 8; j++) {                                               \
      float p = __expf(lg[j] - m_r);                                            \
      psum += p;                                                                \
      pfh[j] = (short)(u16)(__float_as_uint(p) >> 16);                          \
    }                                                                           \
    l_r += psum;                                                                \
    _Pragma("unroll")                                                           \
    for (int dt = 0; dt < 4; dt++) {                                            \
      int row = ql + 16 * dt;                                                   \
      s16x8 bhf = *(const s16x8*)(VhL + row * 72 + hh * 32 + g * 8);            \
      oacc[dt] = __builtin_amdgcn_mfma_f32_16x16x32_bf16(pfh, bhf, oacc[dt], 0, 0, 0); \
    }                                                                           \
  }

  for (int kt0 = 0; kt0 < 36; kt0 += 3) {
    ATTN_TILE(kt0 + 0, wA, wB, hh != 0);   // d=0: wrap iff hh==1
    ATTN_TILE(kt0 + 1, wB, wC, false);     // d=1: never wraps
    ATTN_TILE(kt0 + 2, wC, wA, hh == 0);   // d=2: wrap iff hh==0
  }
#undef ATTN_TILE

  // ---- deferred cross-g reduction of per-lane partial l
  l_r += __shfl_xor(l_r, 16);
  l_r += __shfl_xor(l_r, 32);

  // ---- merge the two key-streams per q-group, write out (packed u32 hi|lo)
  __syncthreads();
  if (hh == 1) {
    if (g == 0) { m_s[q64b] = m_r; l_s[q64b] = l_r; }
#pragma unroll
    for (int dt = 0; dt < 4; dt++)
#pragma unroll
      for (int r = 0; r < 4; r++)
        o_s[(wq * 16 + g * 4 + r) * 68 + ql + 16 * dt] = oacc[dt][r];
  }
  __syncthreads();
  if (hh == 0) {
    float m2 = m_s[q64b];
    float l2 = l_s[q64b];
    float mf = fmaxf(m_r, m2);
    float c1 = __expf(m_r - mf);
    float c2 = __expf(m2 - mf);
    float lf = l_r * c1 + l2 * c2;
    float c1q[4], c2q[4], lfq[4];
#pragma unroll
    for (int r = 0; r < 4; r++) {
      c1q[r] = __shfl(c1, g * 4 + r);
      c2q[r] = __shfl(c2, g * 4 + r);
      lfq[r] = __shfl(lf, g * 4 + r);
    }
    const int b = bh / 12, head = bh - (bh / 12) * 12;
#pragma unroll
    for (int dt = 0; dt < 4; dt++)
#pragma unroll
      for (int r = 0; r < 4; r++) {
        float oo = oacc[dt][r] * c1q[r]
                 + o_s[(wq * 16 + g * 4 + r) * 68 + ql + 16 * dt] * c2q[r];
        float on = oo / lfq[r];
        int s = s0 + wq * 16 + g * 4 + r;
        size_t idx = ((size_t)b * SEQ + s) * 768 + head * 64 + ql + 16 * dt;
        u16 h, l;
        split2(on, h, l);
        aop[idx] = (u32)h | ((u32)l << 16);
      }
  }
}

// ---- proj direct-fragment helpers: A = packed u32 (unpack in-register)
static __device__ __forceinline__ void unpack8(
    const uint4 w0, const uint4 w1, s16x8& h, s16x8& l)
{
  u32 w[8];
  *(uint4*)&w[0] = w0; *(uint4*)&w[4] = w1;
  u32 hw[4], lw[4];
#pragma unroll
  for (int i = 0; i < 4; i++) {
    hw[i] = (w[2*i] & 0xffffu) | (w[2*i+1] << 16);
    lw[i] = (w[2*i] >> 16) | (w[2*i+1] & 0xffff0000u);
  }
  h = *(s16x8*)&hw[0];
  l = *(s16x8*)&lw[0];
}
static __device__ __forceinline__ void loadP(
    const u32* pA, const u16* pBh, const u16* pBl, int kk,
    uint4 aw[4][2], s16x8 bh[4], s16x8 bl[4])
{
#pragma unroll
  for (int mt = 0; mt < 4; mt++) {
    size_t oa = (size_t)mt * 12288 + (size_t)kk * 32;
    aw[mt][0] = *(const uint4*)(pA + oa);
    aw[mt][1] = *(const uint4*)(pA + oa + 4);
    size_t ob = (size_t)mt * 12288 + (size_t)kk * 32;
    bh[mt] = *(const s16x8*)(pBh + ob);
    bl[mt] = *(const s16x8*)(pBl + ob);
  }
}
static __device__ __forceinline__ void mfmaP(
    uint4 aw[4][2], const s16x8 bh[4], const s16x8 bl[4], f32x4 acc[4][4])
{
#pragma unroll
  for (int mt = 0; mt < 4; mt++) {
    s16x8 ah, al;
    unpack8(aw[mt][0], aw[mt][1], ah, al);
#pragma unroll
    for (int nt = 0; nt < 4; nt++) {
      acc[mt][nt] = __builtin_amdgcn_mfma_f32_16x16x32_bf16(ah, bh[nt], acc[mt][nt], 0, 0, 0);
      acc[mt][nt] = __builtin_amdgcn_mfma_f32_16x16x32_bf16(ah, bl[nt], acc[mt][nt], 0, 0, 0);
      acc[mt][nt] = __builtin_amdgcn_mfma_f32_16x16x32_bf16(al, bh[nt], acc[mt][nt], 0, 0, 0);
    }
  }
}

// ---------------- proj GEMM, barrier-free direct-fragment (qkv-style): -> out
__global__ __launch_bounds__(256, 2) void proj_mfma_k(
    const u32* __restrict__ aop,
    const u16* __restrict__ bthi, const u16* __restrict__ btlo,
    const float* __restrict__ bias, float* __restrict__ out)
{
  const int tid = threadIdx.x;
  const int lane = tid & 63, wid = tid >> 6;
  const int g = lane >> 4, ql = lane & 15;
  const int wr = wid >> 1, wc = wid & 1;
  const int c0 = blockIdx.x * 128, r0 = blockIdx.y * 128;

  const u32* pA  = aop  + (size_t)(r0 + wr * 64 + ql) * 768 + g * 8;
  const u16* pBh = bthi + (size_t)(c0 + wc * 64 + ql) * 768 + g * 8;
  const u16* pBl = btlo + (size_t)(c0 + wc * 64 + ql) * 768 + g * 8;

  uint4 Xa[4][2]; s16x8 Xbh[4], Xbl[4];
  uint4 Ya[4][2]; s16x8 Ybh[4], Ybl[4];
  f32x4 acc[4][4] = {};

  loadP(pA, pBh, pBl, 0, Xa, Xbh, Xbl);
  for (int ks = 0; ks < 24; ks += 2) {
    loadP(pA, pBh, pBl, ks + 1, Ya, Ybh, Ybl);
    mfmaP(Xa, Xbh, Xbl, acc);
    if (ks + 2 < 24)
      loadP(pA, pBh, pBl, ks + 2, Xa, Xbh, Xbl);
    mfmaP(Ya, Ybh, Ybl, acc);
  }

  const int col0 = c0 + wc * 64;
  const int row0 = r0 + wr * 64;
  float bb[4];
#pragma unroll
  for (int nt = 0; nt < 4; nt++) bb[nt] = bias[col0 + nt * 16 + ql];
#pragma unroll
  for (int mt = 0; mt < 4; mt++)
#pragma unroll
    for (int nt = 0; nt < 4; nt++)
#pragma unroll
      for (int r = 0; r < 4; r++)
        out[(size_t)(row0 + mt * 16 + g * 4 + r) * 768 + col0 + nt * 16 + ql] =
            acc[mt][nt][r] + bb[nt];
}

extern "C" void kernel_launch(void* const* d_in, const int* in_sizes, int n_in,
                              void* d_out, int out_size, void* d_ws, size_t ws_size,
                              hipStream_t stream) {
  const float* x      = (const float*)d_in[0];
  const float* qkv_w  = (const float*)d_in[1];
  const float* qkv_b  = (const float*)d_in[2];
  const float* proj_w = (const float*)d_in[3];
  const float* proj_b = (const float*)d_in[4];
  const float* rph    = (const float*)d_in[5];
  const float* rpw    = (const float*)d_in[6];
  float* out = (float*)d_out;
  float* ws  = (float*)d_ws;

  const size_t SZ = (size_t)24 * SEQ * HD;   // 3,538,944 elems (== 4608*768)
  float* qbuf = ws;                          // SZ f32
  u16* khi = (u16*)(ws + SZ);                // khi, klo, vhi (+dead slot)
  u16* klo = khi + SZ;
  u16* vhi = klo + SZ;
  u32* aop = (u32*)(ws + 4 * SZ);            // SZ u32 (packed hi|lo)
  u16* wqThi = (u16*)(ws + 5 * SZ);          // 768*2304 x2
  u16* wqTlo = wqThi + 768 * 2304;
  u16* wpThi = wqTlo + 768 * 2304;           // 768*768 x2
  u16* wpTlo = wpThi + 768 * 768;

  conv_wT2_k <<<dim3(48, 12), 256, 0, stream>>>(qkv_w, proj_w,
                                                wqThi, wqTlo, wpThi, wpTlo);
  qkv_mfma_k <<<dim3(18, 36), 256, 0, stream>>>(x, wqThi, wqTlo, qkv_b,
                                                qbuf, khi, klo, vhi);
  attn_k     <<<dim3(24, 36), 512, 0, stream>>>(qbuf, khi, klo, vhi, rph, rpw, aop);
  proj_mfma_k<<<dim3(6, 36), 256, 0, stream>>>(aop, wpThi, wpTlo, proj_b, out);
}

// Round 23
// 427.606 us; speedup vs baseline: 1.1282x; 1.0451x over previous
//
#include <hip/hip_runtime.h>
#include <hip/hip_fp16.h>

#define HD 64
#define SEQ 2304

typedef unsigned short u16;
typedef unsigned int u32;
using f32x4 = __attribute__((ext_vector_type(4))) float;
using s16x8 = __attribute__((ext_vector_type(8))) short;

static __device__ __forceinline__ float bf2f(u16 h) {
  union { float f; u32 u; } a; a.u = ((u32)h) << 16; return a.f;
}
// truncation split: x ~= hi + lo, |err| ~ 2^-16 |x|
static __device__ __forceinline__ void split2(float x, u16& h, u16& l) {
  u32 u = __float_as_uint(x);
  h = (u16)(u >> 16);
  float r = x - __uint_as_float(u & 0xffff0000u);
  l = (u16)(__float_as_uint(r) >> 16);
}
// round-to-nearest-even bf16 (unbiased: used for K and V, consumed single-level)
static __device__ __forceinline__ u16 rne_bf16(float x) {
  u32 u = __float_as_uint(x);
  return (u16)((u + 0x7fffu + ((u >> 16) & 1u)) >> 16);
}

// ---------------- convert + transpose BOTH weights: w[768][N] f32 -> wT[N][768]
// bf16 hi/lo. Grid x: [0,36) -> qkv_w (N=2304), [36,48) -> proj_w (N=768).
__global__ __launch_bounds__(256) void conv_wT2_k(
    const float* __restrict__ wq, const float* __restrict__ wp,
    u16* __restrict__ qhiT, u16* __restrict__ qloT,
    u16* __restrict__ phiT, u16* __restrict__ ploT)
{
  __shared__ u32 t[64][65];
  const int tid = threadIdx.x;
  const bool isq = blockIdx.x < 36;
  const int bx = isq ? blockIdx.x : blockIdx.x - 36;
  const float* src = isq ? wq : wp;
  u16* dhi = isq ? qhiT : phiT;
  u16* dlo = isq ? qloT : ploT;
  const int N = isq ? 2304 : 768;
  const int n0 = bx * 64, k0 = blockIdx.y * 64;
  const int r = tid >> 2, c0 = (tid & 3) * 16;
  const float* sp = src + (size_t)(k0 + r) * N + n0 + c0;
#pragma unroll
  for (int j = 0; j < 16; j += 4) {
    f32x4 v = *(const f32x4*)(sp + j);
#pragma unroll
    for (int e = 0; e < 4; e++) {
      u16 h, l;
      split2(v[e], h, l);
      t[r][c0 + j + e] = (u32)h | ((u32)l << 16);
    }
  }
  __syncthreads();
  u16 hb[16], lb[16];
#pragma unroll
  for (int j = 0; j < 16; j++) {
    u32 p = t[c0 + j][r];
    hb[j] = (u16)(p & 0xffffu);
    lb[j] = (u16)(p >> 16);
  }
  size_t off = (size_t)(n0 + r) * 768 + k0 + c0;
  *(uint4*)(dhi + off)     = *(uint4*)&hb[0];
  *(uint4*)(dhi + off + 8) = *(uint4*)&hb[8];
  *(uint4*)(dlo + off)     = *(uint4*)&lb[0];
  *(uint4*)(dlo + off + 8) = *(uint4*)&lb[8];
}

// ---- qkv direct-fragment helpers: A = raw fp32 (split in-register at use)
static __device__ __forceinline__ void loadF(
    const float* pA, const u16* pBh, const u16* pBl, int kk,
    uint4 aw[4][2], s16x8 bh[4], s16x8 bl[4])
{
#pragma unroll
  for (int mt = 0; mt < 4; mt++) {
    size_t o = (size_t)mt * 12288 + (size_t)kk * 32;   // row-stride 768 elems
    aw[mt][0] = *(const uint4*)(pA + o);       // 4 f32 (bits)
    aw[mt][1] = *(const uint4*)(pA + o + 4);
    bh[mt] = *(const s16x8*)(pBh + o);
    bl[mt] = *(const s16x8*)(pBl + o);
  }
}
static __device__ __forceinline__ void mfmaF(
    uint4 aw[4][2], const s16x8 bh[4], const s16x8 bl[4], f32x4 acc[4][4])
{
#pragma unroll
  for (int mt = 0; mt < 4; mt++) {
    u32 w[8];
    *(uint4*)&w[0] = aw[mt][0]; *(uint4*)&w[4] = aw[mt][1];
    u16 hh[8], ll[8];
#pragma unroll
    for (int j = 0; j < 8; j++)
      split2(__uint_as_float(w[j]), hh[j], ll[j]);
    s16x8 ah = *(s16x8*)&hh[0];
    s16x8 al = *(s16x8*)&ll[0];
#pragma unroll
    for (int nt = 0; nt < 4; nt++) {
      acc[mt][nt] = __builtin_amdgcn_mfma_f32_16x16x32_bf16(ah, bh[nt], acc[mt][nt], 0, 0, 0);
      acc[mt][nt] = __builtin_amdgcn_mfma_f32_16x16x32_bf16(ah, bl[nt], acc[mt][nt], 0, 0, 0);
      acc[mt][nt] = __builtin_amdgcn_mfma_f32_16x16x32_bf16(al, bh[nt], acc[mt][nt], 0, 0, 0);
    }
  }
}

// ---------------- QKV GEMM, barrier-free direct-fragment, fp32-A in-register split:
// -> q fp32 + K (single RNE bf16) + V (single RNE bf16) images.
__global__ __launch_bounds__(256, 2) void qkv_mfma_k(
    const float* __restrict__ x,
    const u16* __restrict__ bthi, const u16* __restrict__ btlo,
    const float* __restrict__ bias,
    float* __restrict__ qbuf, u16* __restrict__ khi, u16* __restrict__ vhi)
{
  __shared__ __align__(16) u16 img[4][4096];   // epilogue only (wave-private)
  const int tid = threadIdx.x;
  const int lane = tid & 63, wid = tid >> 6;
  const int g = lane >> 4, ql = lane & 15;
  const int wr = wid >> 1, wc = wid & 1;
  const int c0 = blockIdx.x * 128, r0 = blockIdx.y * 128;

  const float* pA = x    + (size_t)(r0 + wr * 64 + ql) * 768 + g * 8;
  const u16* pBh = bthi + (size_t)(c0 + wc * 64 + ql) * 768 + g * 8;
  const u16* pBl = btlo + (size_t)(c0 + wc * 64 + ql) * 768 + g * 8;

  uint4 Xa[4][2]; s16x8 Xbh[4], Xbl[4];
  uint4 Ya[4][2]; s16x8 Ybh[4], Ybl[4];
  f32x4 acc[4][4] = {};

  loadF(pA, pBh, pBl, 0, Xa, Xbh, Xbl);
  for (int ks = 0; ks < 24; ks += 2) {
    loadF(pA, pBh, pBl, ks + 1, Ya, Ybh, Ybl);
    mfmaF(Xa, Xbh, Xbl, acc);
    if (ks + 2 < 24)
      loadF(pA, pBh, pBl, ks + 2, Xa, Xbh, Xbl);
    mfmaF(Ya, Ybh, Ybl, acc);
  }

  // ---- epilogue: q fp32 scatter / K,V permuted tile-images via LDS (wave-private)
  const int col0 = c0 + wc * 64;
  const int row0 = r0 + wr * 64;
  const int hb36 = col0 >> 6;
  const int which = hb36 / 12, head = hb36 - (hb36 / 12) * 12;
  const int b = row0 / 2304;
  const int sb = row0 - b * 2304;
  const int bh = b * 12 + head;
  float bb[4];
#pragma unroll
  for (int nt = 0; nt < 4; nt++) bb[nt] = bias[col0 + nt * 16 + ql];
#pragma unroll
  for (int mt = 0; mt < 4; mt++)
#pragma unroll
    for (int nt = 0; nt < 4; nt++)
#pragma unroll
      for (int r = 0; r < 4; r++)
        acc[mt][nt][r] += bb[nt];

  if (which == 0) {
#pragma unroll
    for (int mt = 0; mt < 4; mt++)
#pragma unroll
      for (int nt = 0; nt < 4; nt++)
#pragma unroll
        for (int r = 0; r < 4; r++) {
          int s = sb + mt * 16 + g * 4 + r;
          qbuf[((size_t)bh * SEQ + s) * 64 + nt * 16 + ql] = acc[mt][nt][r];
        }
  } else if (which == 1) {
    // K image: single pass, RNE bf16 (consumed single-level in QK^T; RNE unbiased)
    const int kt = sb >> 6;
    const size_t tile = ((size_t)bh * 36 + kt) * 4096;
    u16* const reg = img[wid];
#pragma unroll
    for (int mt = 0; mt < 4; mt++)
#pragma unroll
      for (int nt = 0; nt < 4; nt++) {
        int pcK = (nt >> 1) * 32 + (ql >> 2) * 8 + (nt & 1) * 4 + (ql & 3);
#pragma unroll
        for (int r = 0; r < 4; r++)
          reg[(mt * 16 + g * 4 + r) * 64 + pcK] = rne_bf16(acc[mt][nt][r]);
      }
    {
      const u16* src = reg + lane * 64;
      u16* dst = khi + tile + lane * 64;
#pragma unroll
      for (int j = 0; j < 8; j++)
        *(uint4*)(dst + j * 8) = *(const uint4*)(src + j * 8);
    }
  } else {
    // V image: single pass, RNE bf16
    const int kt = sb >> 6;
    const size_t tile = ((size_t)bh * 36 + kt) * 4096;
    u16* const reg = img[wid];
#pragma unroll
    for (int mt = 0; mt < 4; mt++)
#pragma unroll
      for (int nt = 0; nt < 4; nt++)
#pragma unroll
        for (int r = 0; r < 4; r++) {
          int off = (nt * 16 + ql) * 64 + (mt >> 1) * 32 + g * 8 + (mt & 1) * 4 + r;
          reg[off] = rne_bf16(acc[mt][nt][r]);
        }
    {
      const u16* src = reg + lane * 64;
      u16* dst = vhi + tile + lane * 64;
#pragma unroll
      for (int j = 0; j < 8; j++)
        *(uint4*)(dst + j * 8) = *(const uint4*)(src + j * 8);
    }
  }
}

// ---------------- Fused attention: K single RNE bf16 -> 2-MFMA QK^T, -33% LDS
// staging traffic, LDS 30.8KB. Otherwise r22 structure (2-barrier, deferred psum,
// hoisted Bw, no setprio, single-MFMA PV).
#define VL_OFF  9216                      // V: [64 d][72]
#define BWS_OFF 18432                     // scratch Bw [48][65]
#define BH_OFF  (BWS_OFF + 48*65*2)       // 24672: Bh [49][65]
#define MS_OFF  31044                     // (24672+6370 -> 31042, +2 align)
#define LS_OFF  (MS_OFF + 256)            // 31300
__global__ __launch_bounds__(512) void attn_k(
    const float* __restrict__ qb,
    const u16* __restrict__ khi, const u16* __restrict__ vhi,
    const float* __restrict__ rph, const float* __restrict__ rpw,
    u32* __restrict__ aop)
{
  __shared__ __align__(16) char pool[LS_OFF + 256];   // 31556 B
  u16* KL  = (u16*)pool;               // [64 key][72]
  u16* VhL = (u16*)(pool + VL_OFF);    // [64 d][72]
  __half* BwS = (__half*)(pool + BWS_OFF); // scratch [48 kw][65 pad]
  __half* Bh  = (__half*)(pool + BH_OFF);  // [49 kh][65 pad]
  float* m_s = (float*)(pool + MS_OFF);    // [64]
  float* l_s = (float*)(pool + LS_OFF);    // [64]
  float* qlds = (float*)pool;              // prologue alias [64][68] f32 (17408B)
  float* o_s  = (float*)pool;              // epilogue alias [64][68] f32

  const int tid  = threadIdx.x;
  const int lane = tid & 63;
  const int wid  = tid >> 6;
  const int g    = lane >> 4;
  const int ql   = lane & 15;
  const int wq   = wid & 3;     // q-group: rows [16*wq, 16*wq+16)
  const int hh   = wid >> 2;    // key-half stream
  const int bh   = blockIdx.x;  // 24
  const int qt   = blockIdx.y;  // 36
  const int s0   = qt * 64;

  // ---- stage Q tile fp32 -> LDS
  {
    int row = tid >> 3, c0 = (tid & 7) * 8;
    const float* src = qb + ((size_t)bh * SEQ + s0 + row) * HD + c0;
    f32x4 v0 = *(const f32x4*)src;
    f32x4 v1 = *(const f32x4*)(src + 4);
    *(f32x4*)&qlds[row * 68 + c0]     = v0;
    *(f32x4*)&qlds[row * 68 + c0 + 4] = v1;
  }
  __syncthreads();

  // ---- Q fragments hi/lo (lane's q = 16*wq + ql)
  s16x8 qfh[2], qfl[2];
  {
    int qrow = wq * 16 + ql;
#pragma unroll
    for (int ds = 0; ds < 2; ds++) {
#pragma unroll
      for (int h2 = 0; h2 < 2; h2++) {
        f32x4 qv = *(const f32x4*)&qlds[qrow * 68 + g * 4 + h2 * 16 + ds * 32];
#pragma unroll
        for (int j = 0; j < 4; j++) {
          u16 hi, lo;
          split2(qv[j], hi, lo);
          qfh[ds][h2 * 4 + j] = (short)hi;
          qfl[ds][h2 * 4 + j] = (short)lo;
        }
      }
    }
  }

  // ---- prefetch tile 0 (K + V only)
  const size_t tbK = (size_t)bh * 36 * 4096;
  const int srow = tid >> 3;
  const int sch  = ((tid & 7) - (srow & 7)) & 7;
  const size_t soff = (size_t)srow * 64 + sch * 8;
  uint4 rkh = *(const uint4*)(khi + tbK + soff);
  uint4 rvh = *(const uint4*)(vhi + tbK + soff);

  // ---- decomposed rel-pos bias build: Bh persistent, Bw into scratch
  for (int i = tid; i < 64 * 96; i += 512) {
    int q = i / 96, j = i - (i / 96) * 96;
    int s = s0 + q;
    int qhg = s / 48, qw = s - qhg * 48;
    const float* tab;
    int ridx, col;
    if (j < 48) { col = j;      ridx = qhg - j + 47;        tab = rph; }
    else        { col = j - 48; ridx = qw - (j - 48) + 47;  tab = rpw; }
    const float* rp = tab + (size_t)ridx * HD;
    const float* qp = &qlds[q * 68];
    float s1 = 0.f;
#pragma unroll 4
    for (int d = 0; d < 64; d += 4) {
      f32x4 a = *(const f32x4*)(qp + d);
      f32x4 bv = *(const f32x4*)(rp + d);
      s1 += a[0]*bv[0] + a[1]*bv[1] + a[2]*bv[2] + a[3]*bv[3];
    }
    if (j < 48) Bh[col * 65 + q] = __float2half_rn(s1);
    else        BwS[col * 65 + q] = __float2half_rn(s1);
  }
  __syncthreads();

  const int q64b = wq * 16 + ql;

  // ---- hoist per-lane Bw values (12 of them), reorder by hh for kt%3 rotation
  float wA[4], wB[4], wC[4];
  {
    float b0[4], b1[4], b2[4];
#pragma unroll
    for (int r = 0; r < 4; r++) {
      b0[r] = __half2float(BwS[(      g * 4 + r) * 65 + q64b]);
      b1[r] = __half2float(BwS[(16 +  g * 4 + r) * 65 + q64b]);
      b2[r] = __half2float(BwS[(32 +  g * 4 + r) * 65 + q64b]);
    }
#pragma unroll
    for (int r = 0; r < 4; r++) {
      wA[r] = hh ? b2[r] : b0[r];   // w[j] = bw[(j + 2*hh) % 3]
      wB[r] = hh ? b0[r] : b1[r];
      wC[r] = hh ? b1[r] : b2[r];
    }
  }

  float m_r = -3.0e38f, l_r = 0.f;   // l_r = per-lane partial (reduced in epilogue)
  f32x4 oacc[4] = {};   // O[q = 4g+r][d = ql + 16*dt]

  // tile body: WA_ = bw for t2=0, WB_ = bw for t2=1; WRAP1 = (u==2), u=(kt+2hh)%3
#define ATTN_TILE(KT, WA_, WB_, WRAP1) {                                        \
    const int kt = (KT);                                                        \
    __syncthreads();                                                            \
    *(uint4*)(KL  + srow * 72 + sch * 8) = rkh;                                 \
    *(uint4*)(VhL + srow * 72 + sch * 8) = rvh;                                 \
    __syncthreads();                                                            \
    if (kt < 35) {                                                              \
      size_t tb = tbK + (size_t)(kt + 1) * 4096;                                \
      rkh = *(const uint4*)(khi + tb + soff);                                   \
      rvh = *(const uint4*)(vhi + tb + soff);                                   \
    }                                                                           \
    f32x4 sacc[2] = {};                                                         \
    _Pragma("unroll")                                                           \
    for (int ds = 0; ds < 2; ds++) {                                            \
      _Pragma("unroll")                                                         \
      for (int t2 = 0; t2 < 2; t2++) {                                          \
        int row = (hh * 2 + t2) * 16 + ql;                                      \
        s16x8 af = *(const s16x8*)(KL + row * 72 + ds * 32 + g * 8);            \
        sacc[t2] = __builtin_amdgcn_mfma_f32_16x16x32_bf16(af, qfh[ds], sacc[t2], 0, 0, 0); \
        sacc[t2] = __builtin_amdgcn_mfma_f32_16x16x32_bf16(af, qfl[ds], sacc[t2], 0, 0, 0); \
      }                                                                         \
    }                                                                           \
    u32 kg0 = (u32)(kt * 64 + hh * 32);                                         \
    u32 kh0 = kg0 / 48u;                                                        \
    float bh0v = __half2float(Bh[kh0 * 65 + q64b]);                             \
    float bh1v = __half2float(Bh[(kh0 + 1) * 65 + q64b]);                       \
    float bhB = (WRAP1) ? bh1v : bh0v;                                          \
    float lg[8];                                                                \
    float tmax = -3.0e38f;                                                      \
    _Pragma("unroll")                                                           \
    for (int r = 0; r < 4; r++) {                                               \
      float x0 = sacc[0][r] * 0.125f + (bh0v + WA_[r]);                         \
      float x1 = sacc[1][r] * 0.125f + (bhB  + WB_[r]);                         \
      lg[r]     = x0;                                                           \
      lg[4 + r] = x1;                                                           \
      tmax = fmaxf(tmax, fmaxf(x0, x1));                                        \
    }                                                                           \
    tmax = fmaxf(tmax, __shfl_xor(tmax, 16));                                   \
    tmax = fmaxf(tmax, __shfl_xor(tmax, 32));                                   \
    if (__any(tmax > m_r + 6.0f)) {                                             \
      float mnew = fmaxf(m_r, tmax);                                            \
      float corr = __expf(m_r - mnew);                                          \
      l_r *= corr;                                                              \
      m_r = mnew;                                                               \
      float cq[4];                                                              \
      _Pragma("unroll")                                                         \
      for (int r = 0; r < 4; r++) cq[r] = __shfl(corr, g * 4 + r);              \
      _Pragma("unroll")                                                         \
      for (int dt = 0; dt < 4; dt++)                                            \
        _Pragma("unroll")                                                       \
        for (int r = 0; r < 4; r++) oacc[dt][r] *= cq[r];                       \
    }                                                                           \
    float psum = 0.f;                                                           \
    s16x8 pfh;                                                                  \
    _Pragma("unroll")                                                           \
    for (int j = 0; j < 8; j++) {                                               \
      float p = __expf(lg[j] - m_r);                                            \
      psum += p;                                                                \
      pfh[j] = (short)(u16)(__float_as_uint(p) >> 16);                          \
    }                                                                           \
    l_r += psum;                                                                \
    _Pragma("unroll")                                                           \
    for (int dt = 0; dt < 4; dt++) {                                            \
      int row = ql + 16 * dt;                                                   \
      s16x8 bhf = *(const s16x8*)(VhL + row * 72 + hh * 32 + g * 8);            \
      oacc[dt] = __builtin_amdgcn_mfma_f32_16x16x32_bf16(pfh, bhf, oacc[dt], 0, 0, 0); \
    }                                                                           \
  }

  for (int kt0 = 0; kt0 < 36; kt0 += 3) {
    ATTN_TILE(kt0 + 0, wA, wB, hh != 0);   // d=0: wrap iff hh==1
    ATTN_TILE(kt0 + 1, wB, wC, false);     // d=1: never wraps
    ATTN_TILE(kt0 + 2, wC, wA, hh == 0);   // d=2: wrap iff hh==0
  }
#undef ATTN_TILE

  // ---- deferred cross-g reduction of per-lane partial l
  l_r += __shfl_xor(l_r, 16);
  l_r += __shfl_xor(l_r, 32);

  // ---- merge the two key-streams per q-group, write out (packed u32 hi|lo)
  __syncthreads();
  if (hh == 1) {
    if (g == 0) { m_s[q64b] = m_r; l_s[q64b] = l_r; }
#pragma unroll
    for (int dt = 0; dt < 4; dt++)
#pragma unroll
      for (int r = 0; r < 4; r++)
        o_s[(wq * 16 + g * 4 + r) * 68 + ql + 16 * dt] = oacc[dt][r];
  }
  __syncthreads();
  if (hh == 0) {
    float m2 = m_s[q64b];
    float l2 = l_s[q64b];
    float mf = fmaxf(m_r, m2);
    float c1 = __expf(m_r - mf);
    float c2 = __expf(m2 - mf);
    float lf = l_r * c1 + l2 * c2;
    float c1q[4], c2q[4], lfq[4];
#pragma unroll
    for (int r = 0; r < 4; r++) {
      c1q[r] = __shfl(c1, g * 4 + r);
      c2q[r] = __shfl(c2, g * 4 + r);
      lfq[r] = __shfl(lf, g * 4 + r);
    }
    const int b = bh / 12, head = bh - (bh / 12) * 12;
#pragma unroll
    for (int dt = 0; dt < 4; dt++)
#pragma unroll
      for (int r = 0; r < 4; r++) {
        float oo = oacc[dt][r] * c1q[r]
                 + o_s[(wq * 16 + g * 4 + r) * 68 + ql + 16 * dt] * c2q[r];
        float on = oo / lfq[r];
        int s = s0 + wq * 16 + g * 4 + r;
        size_t idx = ((size_t)b * SEQ + s) * 768 + head * 64 + ql + 16 * dt;
        u16 h, l;
        split2(on, h, l);
        aop[idx] = (u32)h | ((u32)l << 16);
      }
  }
}

// ---- proj direct-fragment helpers: A = packed u32 (unpack in-register)
static __device__ __forceinline__ void unpack8(
    const uint4 w0, const uint4 w1, s16x8& h, s16x8& l)
{
  u32 w[8];
  *(uint4*)&w[0] = w0; *(uint4*)&w[4] = w1;
  u32 hw[4], lw[4];
#pragma unroll
  for (int i = 0; i < 4; i++) {
    hw[i] = (w[2*i] & 0xffffu) | (w[2*i+1] << 16);
    lw[i] = (w[2*i] >> 16) | (w[2*i+1] & 0xffff0000u);
  }
  h = *(s16x8*)&hw[0];
  l = *(s16x8*)&lw[0];
}
static __device__ __forceinline__ void loadP(
    const u32* pA, const u16* pBh, const u16* pBl, int kk,
    uint4 aw[4][2], s16x8 bh[4], s16x8 bl[4])
{
#pragma unroll
  for (int mt = 0; mt < 4; mt++) {
    size_t oa = (size_t)mt * 12288 + (size_t)kk * 32;
    aw[mt][0] = *(const uint4*)(pA + oa);
    aw[mt][1] = *(const uint4*)(pA + oa + 4);
    size_t ob = (size_t)mt * 12288 + (size_t)kk * 32;
    bh[mt] = *(const s16x8*)(pBh + ob);
    bl[mt] = *(const s16x8*)(pBl + ob);
  }
}
static __device__ __forceinline__ void mfmaP(
    uint4 aw[4][2], const s16x8 bh[4], const s16x8 bl[4], f32x4 acc[4][4])
{
#pragma unroll
  for (int mt = 0; mt < 4; mt++) {
    s16x8 ah, al;
    unpack8(aw[mt][0], aw[mt][1], ah, al);
#pragma unroll
    for (int nt = 0; nt < 4; nt++) {
      acc[mt][nt] = __builtin_amdgcn_mfma_f32_16x16x32_bf16(ah, bh[nt], acc[mt][nt], 0, 0, 0);
      acc[mt][nt] = __builtin_amdgcn_mfma_f32_16x16x32_bf16(ah, bl[nt], acc[mt][nt], 0, 0, 0);
      acc[mt][nt] = __builtin_amdgcn_mfma_f32_16x16x32_bf16(al, bh[nt], acc[mt][nt], 0, 0, 0);
    }
  }
}

// ---------------- proj GEMM, barrier-free direct-fragment (qkv-style): -> out
__global__ __launch_bounds__(256, 2) void proj_mfma_k(
    const u32* __restrict__ aop,
    const u16* __restrict__ bthi, const u16* __restrict__ btlo,
    const float* __restrict__ bias, float* __restrict__ out)
{
  const int tid = threadIdx.x;
  const int lane = tid & 63, wid = tid >> 6;
  const int g = lane >> 4, ql = lane & 15;
  const int wr = wid >> 1, wc = wid & 1;
  const int c0 = blockIdx.x * 128, r0 = blockIdx.y * 128;

  const u32* pA  = aop  + (size_t)(r0 + wr * 64 + ql) * 768 + g * 8;
  const u16* pBh = bthi + (size_t)(c0 + wc * 64 + ql) * 768 + g * 8;
  const u16* pBl = btlo + (size_t)(c0 + wc * 64 + ql) * 768 + g * 8;

  uint4 Xa[4][2]; s16x8 Xbh[4], Xbl[4];
  uint4 Ya[4][2]; s16x8 Ybh[4], Ybl[4];
  f32x4 acc[4][4] = {};

  loadP(pA, pBh, pBl, 0, Xa, Xbh, Xbl);
  for (int ks = 0; ks < 24; ks += 2) {
    loadP(pA, pBh, pBl, ks + 1, Ya, Ybh, Ybl);
    mfmaP(Xa, Xbh, Xbl, acc);
    if (ks + 2 < 24)
      loadP(pA, pBh, pBl, ks + 2, Xa, Xbh, Xbl);
    mfmaP(Ya, Ybh, Ybl, acc);
  }

  const int col0 = c0 + wc * 64;
  const int row0 = r0 + wr * 64;
  float bb[4];
#pragma unroll
  for (int nt = 0; nt < 4; nt++) bb[nt] = bias[col0 + nt * 16 + ql];
#pragma unroll
  for (int mt = 0; mt < 4; mt++)
#pragma unroll
    for (int nt = 0; nt < 4; nt++)
#pragma unroll
      for (int r = 0; r < 4; r++)
        out[(size_t)(row0 + mt * 16 + g * 4 + r) * 768 + col0 + nt * 16 + ql] =
            acc[mt][nt][r] + bb[nt];
}

extern "C" void kernel_launch(void* const* d_in, const int* in_sizes, int n_in,
                              void* d_out, int out_size, void* d_ws, size_t ws_size,
                              hipStream_t stream) {
  const float* x      = (const float*)d_in[0];
  const float* qkv_w  = (const float*)d_in[1];
  const float* qkv_b  = (const float*)d_in[2];
  const float* proj_w = (const float*)d_in[3];
  const float* proj_b = (const float*)d_in[4];
  const float* rph    = (const float*)d_in[5];
  const float* rpw    = (const float*)d_in[6];
  float* out = (float*)d_out;
  float* ws  = (float*)d_ws;

  const size_t SZ = (size_t)24 * SEQ * HD;   // 3,538,944 elems (== 4608*768)
  float* qbuf = ws;                          // SZ f32
  u16* khi = (u16*)(ws + SZ);                // K image (RNE bf16)
  u16* vhi = khi + SZ;                       // V image (RNE bf16)
  u32* aop = (u32*)(ws + 4 * SZ);            // SZ u32 (packed hi|lo)
  u16* wqThi = (u16*)(ws + 5 * SZ);          // 768*2304 x2
  u16* wqTlo = wqThi + 768 * 2304;
  u16* wpThi = wqTlo + 768 * 2304;           // 768*768 x2
  u16* wpTlo = wpThi + 768 * 768;

  conv_wT2_k <<<dim3(48, 12), 256, 0, stream>>>(qkv_w, proj_w,
                                                wqThi, wqTlo, wpThi, wpTlo);
  qkv_mfma_k <<<dim3(18, 36), 256, 0, stream>>>(x, wqThi, wqTlo, qkv_b,
                                                qbuf, khi, vhi);
  attn_k     <<<dim3(24, 36), 512, 0, stream>>>(qbuf, khi, vhi, rph, rpw, aop);
  proj_mfma_k<<<dim3(6, 36), 256, 0, stream>>>(aop, wpThi, wpTlo, proj_b, out);
}